// Round 1
// baseline (1782.771 us; speedup 1.0000x reference)
//
#include <hip/hip_runtime.h>
#include <hip/hip_fp16.h>
#include <math.h>

#define NN 100000
#define NE 1600000
#define NB ((NN + 255) >> 8)   // 391 buckets of 256 nodes
#define CHUNK 8192
#define CAP 8192

typedef __attribute__((ext_vector_type(4))) float floatx4;
typedef __attribute__((ext_vector_type(8))) short shortx8;

// ---------------- bucketed CSR build ----------------

__global__ __launch_bounds__(256)
void coarse_hist(const int* __restrict__ ei, int* __restrict__ bucket_cnt, int E) {
    __shared__ int h[512];
    int t = threadIdx.x;
    for (int i = t; i < 512; i += 256) h[i] = 0;
    __syncthreads();
    int base = blockIdx.x * CHUNK;
    int lim = min(base + CHUNK, E);
    for (int e = base + t; e < lim; e += 256) {
        int d = ei[E + e];
        atomicAdd(&h[d >> 8], 1);
    }
    __syncthreads();
    for (int i = t; i < 512; i += 256)
        if (h[i]) atomicAdd(&bucket_cnt[i], h[i]);
}

__global__ void scan_buckets(const int* __restrict__ bucket_cnt,
                             int* __restrict__ bucket_base,
                             int* __restrict__ bucket_fill) {
    __shared__ int sh[512];
    int t = threadIdx.x;  // 512 threads
    int v = (t < NB) ? bucket_cnt[t] : 0;
    sh[t] = v;
    __syncthreads();
    for (int off = 1; off < 512; off <<= 1) {
        int u = (t >= off) ? sh[t - off] : 0;
        __syncthreads();
        sh[t] += u;
        __syncthreads();
    }
    int ex = (t == 0) ? 0 : sh[t - 1];
    if (t <= NB) bucket_base[t] = ex;
    if (t < NB) bucket_fill[t] = ex;
}

__global__ __launch_bounds__(256)
void coarse_scatter(const int* __restrict__ ei, int* __restrict__ bucket_fill,
                    unsigned long long* __restrict__ pairs, int E) {
    __shared__ int h[512];
    __shared__ int base[512];
    int t = threadIdx.x;
    for (int i = t; i < 512; i += 256) h[i] = 0;
    __syncthreads();
    int cbase = blockIdx.x * CHUNK;
    int lim = min(cbase + CHUNK, E);
    for (int e = cbase + t; e < lim; e += 256) {
        int d = ei[E + e];
        atomicAdd(&h[d >> 8], 1);
    }
    __syncthreads();
    for (int i = t; i < 512; i += 256)
        base[i] = h[i] ? atomicAdd(&bucket_fill[i], h[i]) : 0;
    __syncthreads();
    for (int i = t; i < 512; i += 256) h[i] = 0;
    __syncthreads();
    for (int e = cbase + t; e < lim; e += 256) {
        int s = ei[e];
        int d = ei[E + e];
        int b = d >> 8;
        int r = atomicAdd(&h[b], 1);
        pairs[base[b] + r] =
            ((unsigned long long)(unsigned)d << 32) | (unsigned)s;
    }
}

__global__ __launch_bounds__(256)
void fine_csr(const unsigned long long* __restrict__ pairs,
              const int* __restrict__ bucket_base,
              int* __restrict__ rowptr, int* __restrict__ colid,
              float* __restrict__ dinv, int n) {
    __shared__ int hist[256];
    __shared__ int offs[256];
    __shared__ int rank[256];
    __shared__ int lbuf[CAP];
    int b = blockIdx.x, t = threadIdx.x;
    int beg = bucket_base[b], end = bucket_base[b + 1];
    int cnt = end - beg;
    hist[t] = 0; rank[t] = 0;
    __syncthreads();
    for (int i = t; i < cnt; i += 256) {
        int d = (int)(pairs[beg + i] >> 32);
        atomicAdd(&hist[d & 255], 1);
    }
    __syncthreads();
    int v = hist[t];
    offs[t] = v;
    __syncthreads();
    for (int off = 1; off < 256; off <<= 1) {
        int u = (t >= off) ? offs[t - off] : 0;
        __syncthreads();
        offs[t] += u;
        __syncthreads();
    }
    int ex = (t == 0) ? 0 : offs[t - 1];
    int node = (b << 8) + t;
    if (node < n) {
        rowptr[node] = beg + ex;
        dinv[node] = rsqrtf((float)v + 1.0f);
    } else if (node == n) {
        rowptr[n] = beg + ex;
    }
    __syncthreads();
    offs[t] = ex;
    __syncthreads();
    for (int i = t; i < cnt; i += 256) {
        unsigned long long p = pairs[beg + i];
        int d = (int)(p >> 32) & 255;
        int s = (int)(p & 0xffffffffu);
        int r = atomicAdd(&rank[d], 1);
        lbuf[offs[d] + r] = s;
    }
    __syncthreads();
    for (int i = t; i < cnt; i += 256) colid[beg + i] = lbuf[i];
}

// ---------------- weight prep: W[K][OUT] fp32 -> swizzled bf16 hi/lo fragments ----------------

__global__ void wsplit_kernel(const float* __restrict__ W,
                              unsigned short* __restrict__ Wsw,
                              int K, int OUT) {
    int i = blockIdx.x * 256 + threadIdx.x;
    if (i < K * OUT) {
        int k = i / OUT, o = i % OUT;
        float w = W[i];
        unsigned u = __float_as_uint(w);
        float r = w - __uint_as_float(u & 0xFFFF0000u);
        int NT = OUT >> 4;
        int ktc = k >> 5, q = (k >> 3) & 3, j = k & 7;
        int nt = o >> 4, mm = o & 15;
        int lane = (q << 4) | mm;
        size_t base = ((((size_t)(ktc * NT + nt) * 2) * 64 + lane) << 3) + j;
        Wsw[base] = (unsigned short)(u >> 16);
        Wsw[base + 512] = (unsigned short)(__float_as_uint(r) >> 16);  // h=1: +64*8
    }
}

// ---------------- MFMA GEMM ----------------
// Y16 layout is CHUNK-MAJOR: Y[(nt*N + row)*16 + m], chunk = nt (16 features).
// Two input pointers: columns [0,K1) from X1 (stride K1), [K1,K) from X2 (stride K-K1).

__device__ __forceinline__ void split8(const float* v, shortx8& hi, shortx8& lo) {
#pragma unroll
    for (int i = 0; i < 8; i++) {
        unsigned u = __float_as_uint(v[i]);
        float r = v[i] - __uint_as_float(u & 0xFFFF0000u);
        hi[i] = (short)(u >> 16);
        lo[i] = (short)(__float_as_uint(r) >> 16);
    }
}

template <int OUT, int K, int K1>
__global__ __launch_bounds__(512)
void gemm_mfma(const float* __restrict__ X1, const float* __restrict__ X2,
               const unsigned short* __restrict__ Wsw,
               const float* __restrict__ dinv,
               __half* __restrict__ Y, int ntiles) {
    constexpr int NT = OUT / 16;
    constexpr int NKTC = K / 32;
    constexpr int K2 = K - K1;
    constexpr int PERC = OUT * 128;  // bytes per ktc chunk
    constexpr int CSZ = (65536 / PERC < NKTC) ? (65536 / PERC) : NKTC;
    __shared__ __align__(16) unsigned short lds[CSZ * PERC / 2];

    const int t = threadIdx.x;
    const int wave = t >> 6, lane = t & 63;
    const int m = lane & 15, q = lane >> 4;
    const int tile = blockIdx.x * 8 + wave;
    const bool act = tile < ntiles;
    const int row = act ? tile * 16 + m : 0;
    const int nfull = ntiles * 16;
    const float* ap1 = X1 + (size_t)row * K1 + q * 8;
    const float* ap2 = (K2 > 0) ? (X2 + (size_t)row * K2 + q * 8) : X1;

    floatx4 acc[NT];
#pragma unroll
    for (int nt = 0; nt < NT; nt++) acc[nt] = (floatx4){0.f, 0.f, 0.f, 0.f};

#pragma unroll
    for (int c0 = 0; c0 < NKTC; c0 += CSZ) {
        const int cl = (NKTC - c0 < CSZ) ? (NKTC - c0) : CSZ;
        if (c0 != 0) __syncthreads();
        {
            const float4* gs = (const float4*)Wsw + (size_t)c0 * (PERC / 16);
            float4* ld = (float4*)lds;
            int tot = cl * (PERC / 16);
            for (int i = t; i < tot; i += 512) ld[i] = gs[i];
        }
        __syncthreads();
        if (act) {
#pragma unroll
            for (int ktc = 0; ktc < cl; ktc++) {
                const int kg = (c0 + ktc) * 32;
                const float* p = (kg < K1) ? (ap1 + kg) : (ap2 + (kg - K1));
                float av[8];
                *(float4*)&av[0] = *(const float4*)(p);
                *(float4*)&av[4] = *(const float4*)(p + 4);
                shortx8 ahi, alo;
                split8(av, ahi, alo);
#pragma unroll
                for (int nt = 0; nt < NT; nt++) {
                    const unsigned short* fb =
                        lds + ((((ktc * NT + nt) * 2) * 64 + lane) << 3);
                    shortx8 bhi = *(const shortx8*)fb;
                    shortx8 blo = *(const shortx8*)(fb + 512);
                    acc[nt] = __builtin_amdgcn_mfma_f32_16x16x32_bf16(ahi, bhi, acc[nt], 0, 0, 0);
                    acc[nt] = __builtin_amdgcn_mfma_f32_16x16x32_bf16(ahi, blo, acc[nt], 0, 0, 0);
                    acc[nt] = __builtin_amdgcn_mfma_f32_16x16x32_bf16(alo, bhi, acc[nt], 0, 0, 0);
                }
            }
        }
    }

    if (act) {
        float di[4];
#pragma unroll
        for (int r = 0; r < 4; r++) di[r] = dinv[tile * 16 + q * 4 + r];
#pragma unroll
        for (int nt = 0; nt < NT; nt++) {
#pragma unroll
            for (int r = 0; r < 4; r++) {
                int orow = tile * 16 + q * 4 + r;
                Y[((size_t)nt * nfull + orow) * 16 + m] =
                    __float2half_rn(acc[nt][r] * di[r]);
            }
        }
    }
}

// ---------------- chunked propagation ----------------
// H16 chunk-major: base = hs + c*n*8 (half2 units); row-chunk = 32 B (8 half2).
// chunk = blockIdx % NCH so the XCD round-robin pins each 3.2 MB chunk to one
// XCD's 4 MiB L2 -> gather misses become compulsory-only.
// Wave = 1 node; 8 edge slots x 8 half2 feature lanes; shfl_xor reduce over slots.

template <int NCH, bool TANH>
__global__ __launch_bounds__(512)
void prop_chunk(const __half2* __restrict__ hs, const float* __restrict__ dinv,
                const int* __restrict__ rowptr, const int* __restrict__ colid,
                const float* __restrict__ bias, float* __restrict__ out,
                int ldo, int n) {
    int bid = blockIdx.x;
    int c = bid & (NCH - 1);
    int nb = bid / NCH;
    int wave = threadIdx.x >> 6, lane = threadIdx.x & 63;
    int node = nb * 8 + wave;
    if (node >= n) return;
    int slot = lane >> 3, f = lane & 7;
    int beg = rowptr[node], end = rowptr[node + 1];
    const __half2* __restrict__ base = hs + (size_t)c * n * 8;

    float ax = 0.f, ay = 0.f, bx = 0.f, by = 0.f;
    int e = beg + slot;
    for (; e + 8 < end; e += 16) {
        int s0 = __builtin_nontemporal_load(colid + e);
        int s1 = __builtin_nontemporal_load(colid + e + 8);
        float2 v0 = __half22float2(base[(unsigned)(s0 * 8 + f)]);
        float2 v1 = __half22float2(base[(unsigned)(s1 * 8 + f)]);
        ax += v0.x; ay += v0.y; bx += v1.x; by += v1.y;
    }
    if (e < end) {
        int s = __builtin_nontemporal_load(colid + e);
        float2 v = __half22float2(base[(unsigned)(s * 8 + f)]);
        ax += v.x; ay += v.y;
    }
    ax += bx; ay += by;
    ax += __shfl_xor(ax, 8);  ay += __shfl_xor(ay, 8);
    ax += __shfl_xor(ax, 16); ay += __shfl_xor(ay, 16);
    ax += __shfl_xor(ax, 32); ay += __shfl_xor(ay, 32);

    float2 sf = __half22float2(base[(unsigned)(node * 8 + f)]);
    float di = dinv[node];
    float2 bb = *(const float2*)(bias + c * 16 + 2 * f);
    float ox = di * (ax + sf.x) + bb.x;
    float oy = di * (ay + sf.y) + bb.y;
    if (TANH) { ox = tanhf(ox); oy = tanhf(oy); }
    if (slot == 0) {
        union { float2 f2; unsigned long long u; } cv;
        cv.f2 = make_float2(ox, oy);
        __builtin_nontemporal_store(
            cv.u, (unsigned long long*)(out + (size_t)node * ldo + c * 16 + 2 * f));
    }
}

// ---------------- launch ----------------

extern "C" void kernel_launch(void* const* d_in, const int* in_sizes, int n_in,
                              void* d_out, int out_size, void* d_ws, size_t ws_size,
                              hipStream_t stream) {
    const int n = NN, E = NE;
    const float* feature   = (const float*)d_in[0];
    const float* condition = (const float*)d_in[1];
    const int*   ei        = (const int*)d_in[2];
    const float* W_e1 = (const float*)d_in[3];  const float* b_e1 = (const float*)d_in[4];
    const float* W_e2 = (const float*)d_in[5];  const float* b_e2 = (const float*)d_in[6];
    const float* W_e3 = (const float*)d_in[7];  const float* b_e3 = (const float*)d_in[8];
    const float* W_d1 = (const float*)d_in[9];  const float* b_d1 = (const float*)d_in[10];
    const float* W_d2 = (const float*)d_in[11]; const float* b_d2 = (const float*)d_in[12];
    const float* W_d3 = (const float*)d_in[13]; const float* b_d3 = (const float*)d_in[14];
    float* out = (float*)d_out;

    float*  A    = (float*)d_ws;                    // n*160 floats (slot kept)
    __half* H16  = (__half*)(A + (size_t)n * 160);  // n*128 halves
    float*  dinv = (float*)(H16 + (size_t)n * 128); // n
    int* rowptr  = (int*)(dinv + n);                // n+1
    int* colid   = rowptr + n + 1;                  // E
    uintptr_t pp = (uintptr_t)(colid + E);
    pp = (pp + 15) & ~(uintptr_t)15;
    unsigned long long* pairs = (unsigned long long*)pp;  // E
    int* bucket_cnt  = (int*)(pairs + E);           // 512
    int* bucket_base = bucket_cnt + 512;            // 512
    int* bucket_fill = bucket_base + 512;           // 512
    uintptr_t wp = (uintptr_t)(bucket_fill + 512);
    wp = (wp + 15) & ~(uintptr_t)15;
    unsigned short* wt = (unsigned short*)wp;
    unsigned short* e1w = wt;              unsigned short* e2w = e1w + 160 * 128 * 2;
    unsigned short* e3w = e2w + 128*128*2; unsigned short* d1w = e3w + 128 * 64 * 2;
    unsigned short* d2w = d1w + 96*128*2;  unsigned short* d3w = d2w + 128 * 128 * 2;

    hipMemsetAsync(bucket_cnt, 0, 512 * sizeof(int), stream);

    int nbc = (E + CHUNK - 1) / CHUNK;
    coarse_hist<<<nbc, 256, 0, stream>>>(ei, bucket_cnt, E);
    scan_buckets<<<1, 512, 0, stream>>>(bucket_cnt, bucket_base, bucket_fill);
    coarse_scatter<<<nbc, 256, 0, stream>>>(ei, bucket_fill, pairs, E);
    fine_csr<<<NB, 256, 0, stream>>>(pairs, bucket_base, rowptr, colid, dinv, n);

    wsplit_kernel<<<(160*128 + 255)/256, 256, 0, stream>>>(W_e1, e1w, 160, 128);
    wsplit_kernel<<<(128*128 + 255)/256, 256, 0, stream>>>(W_e2, e2w, 128, 128);
    wsplit_kernel<<<(128*64  + 255)/256, 256, 0, stream>>>(W_e3, e3w, 128, 64);
    wsplit_kernel<<<(96*128  + 255)/256, 256, 0, stream>>>(W_d1, d1w, 96, 128);
    wsplit_kernel<<<(128*128 + 255)/256, 256, 0, stream>>>(W_d2, d2w, 128, 128);
    wsplit_kernel<<<(128*128 + 255)/256, 256, 0, stream>>>(W_d3, d3w, 128, 128);

    const int ntiles = n / 16;          // 6250 exactly
    const int gb = (ntiles + 7) / 8;    // 8 waves per block
    const int pnb = (n + 7) / 8;        // 12500 node-blocks (8 nodes/block)

    // encoder (e1 reads feature+condition directly; concat eliminated)
    gemm_mfma<128, 160, 128><<<gb, 512, 0, stream>>>(feature, condition, e1w, dinv, H16, ntiles);
    prop_chunk<8, true><<<8 * pnb, 512, 0, stream>>>((const __half2*)H16, dinv, rowptr, colid, b_e1, A, 128, n);
    gemm_mfma<128, 128, 128><<<gb, 512, 0, stream>>>(A, nullptr, e2w, dinv, H16, ntiles);
    prop_chunk<8, true><<<8 * pnb, 512, 0, stream>>>((const __half2*)H16, dinv, rowptr, colid, b_e2, A, 128, n);
    gemm_mfma<64, 128, 128><<<gb, 512, 0, stream>>>(A, nullptr, e3w, dinv, H16, ntiles);
    prop_chunk<4, false><<<4 * pnb, 512, 0, stream>>>((const __half2*)H16, dinv, rowptr, colid, b_e3, A, 64, n);

    // decoder (d1 reads z (ldo=64) + condition directly; condcopy eliminated)
    gemm_mfma<128, 96, 64><<<gb, 512, 0, stream>>>(A, condition, d1w, dinv, H16, ntiles);
    prop_chunk<8, true><<<8 * pnb, 512, 0, stream>>>((const __half2*)H16, dinv, rowptr, colid, b_d1, A, 128, n);
    gemm_mfma<128, 128, 128><<<gb, 512, 0, stream>>>(A, nullptr, d2w, dinv, H16, ntiles);
    prop_chunk<8, true><<<8 * pnb, 512, 0, stream>>>((const __half2*)H16, dinv, rowptr, colid, b_d2, A, 128, n);
    gemm_mfma<128, 128, 128><<<gb, 512, 0, stream>>>(A, nullptr, d3w, dinv, H16, ntiles);
    prop_chunk<8, false><<<8 * pnb, 512, 0, stream>>>((const __half2*)H16, dinv, rowptr, colid, b_d3, out, 128, n);
}

// Round 2
// 1303.237 us; speedup vs baseline: 1.3680x; 1.3680x over previous
//
#include <hip/hip_runtime.h>
#include <hip/hip_fp16.h>
#include <math.h>

#define NN 100000
#define NE 1600000
#define NB ((NN + 255) >> 8)   // 391 buckets of 256 nodes
#define CHUNK 8192
#define CAP 8192

typedef __attribute__((ext_vector_type(4))) float floatx4;
typedef __attribute__((ext_vector_type(8))) short shortx8;

// ---------------- bucketed CSR build ----------------

__global__ __launch_bounds__(256)
void coarse_hist(const int* __restrict__ ei, int* __restrict__ bucket_cnt, int E) {
    __shared__ int h[512];
    int t = threadIdx.x;
    for (int i = t; i < 512; i += 256) h[i] = 0;
    __syncthreads();
    int base = blockIdx.x * CHUNK;
    int lim = min(base + CHUNK, E);
    for (int e = base + t; e < lim; e += 256) {
        int d = ei[E + e];
        atomicAdd(&h[d >> 8], 1);
    }
    __syncthreads();
    for (int i = t; i < 512; i += 256)
        if (h[i]) atomicAdd(&bucket_cnt[i], h[i]);
}

__global__ void scan_buckets(const int* __restrict__ bucket_cnt,
                             int* __restrict__ bucket_base,
                             int* __restrict__ bucket_fill) {
    __shared__ int sh[512];
    int t = threadIdx.x;  // 512 threads
    int v = (t < NB) ? bucket_cnt[t] : 0;
    sh[t] = v;
    __syncthreads();
    for (int off = 1; off < 512; off <<= 1) {
        int u = (t >= off) ? sh[t - off] : 0;
        __syncthreads();
        sh[t] += u;
        __syncthreads();
    }
    int ex = (t == 0) ? 0 : sh[t - 1];
    if (t <= NB) bucket_base[t] = ex;
    if (t < NB) bucket_fill[t] = ex;
}

__global__ __launch_bounds__(256)
void coarse_scatter(const int* __restrict__ ei, int* __restrict__ bucket_fill,
                    unsigned long long* __restrict__ pairs, int E) {
    __shared__ int h[512];
    __shared__ int base[512];
    int t = threadIdx.x;
    for (int i = t; i < 512; i += 256) h[i] = 0;
    __syncthreads();
    int cbase = blockIdx.x * CHUNK;
    int lim = min(cbase + CHUNK, E);
    for (int e = cbase + t; e < lim; e += 256) {
        int d = ei[E + e];
        atomicAdd(&h[d >> 8], 1);
    }
    __syncthreads();
    for (int i = t; i < 512; i += 256)
        base[i] = h[i] ? atomicAdd(&bucket_fill[i], h[i]) : 0;
    __syncthreads();
    for (int i = t; i < 512; i += 256) h[i] = 0;
    __syncthreads();
    for (int e = cbase + t; e < lim; e += 256) {
        int s = ei[e];
        int d = ei[E + e];
        int b = d >> 8;
        int r = atomicAdd(&h[b], 1);
        pairs[base[b] + r] =
            ((unsigned long long)(unsigned)d << 32) | (unsigned)s;
    }
}

__global__ __launch_bounds__(256)
void fine_csr(const unsigned long long* __restrict__ pairs,
              const int* __restrict__ bucket_base,
              int* __restrict__ rowptr, int* __restrict__ colid,
              float* __restrict__ dinv, int n) {
    __shared__ int hist[256];
    __shared__ int offs[256];
    __shared__ int rank[256];
    __shared__ int lbuf[CAP];
    int b = blockIdx.x, t = threadIdx.x;
    int beg = bucket_base[b], end = bucket_base[b + 1];
    int cnt = end - beg;
    hist[t] = 0; rank[t] = 0;
    __syncthreads();
    for (int i = t; i < cnt; i += 256) {
        int d = (int)(pairs[beg + i] >> 32);
        atomicAdd(&hist[d & 255], 1);
    }
    __syncthreads();
    int v = hist[t];
    offs[t] = v;
    __syncthreads();
    for (int off = 1; off < 256; off <<= 1) {
        int u = (t >= off) ? offs[t - off] : 0;
        __syncthreads();
        offs[t] += u;
        __syncthreads();
    }
    int ex = (t == 0) ? 0 : offs[t - 1];
    int node = (b << 8) + t;
    if (node < n) {
        rowptr[node] = beg + ex;
        dinv[node] = rsqrtf((float)v + 1.0f);
    } else if (node == n) {
        rowptr[n] = beg + ex;
    }
    __syncthreads();
    offs[t] = ex;
    __syncthreads();
    for (int i = t; i < cnt; i += 256) {
        unsigned long long p = pairs[beg + i];
        int d = (int)(p >> 32) & 255;
        int s = (int)(p & 0xffffffffu);
        int r = atomicAdd(&rank[d], 1);
        lbuf[offs[d] + r] = s;
    }
    __syncthreads();
    for (int i = t; i < cnt; i += 256) colid[beg + i] = lbuf[i];
}

// ---------------- weight prep: W[K][OUT] fp32 -> swizzled bf16 hi/lo fragments ----------------

__global__ void wsplit_kernel(const float* __restrict__ W,
                              unsigned short* __restrict__ Wsw,
                              int K, int OUT) {
    int i = blockIdx.x * 256 + threadIdx.x;
    if (i < K * OUT) {
        int k = i / OUT, o = i % OUT;
        float w = W[i];
        unsigned u = __float_as_uint(w);
        float r = w - __uint_as_float(u & 0xFFFF0000u);
        int NT = OUT >> 4;
        int ktc = k >> 5, q = (k >> 3) & 3, j = k & 7;
        int nt = o >> 4, mm = o & 15;
        int lane = (q << 4) | mm;
        size_t base = ((((size_t)(ktc * NT + nt) * 2) * 64 + lane) << 3) + j;
        Wsw[base] = (unsigned short)(u >> 16);
        Wsw[base + 512] = (unsigned short)(__float_as_uint(r) >> 16);  // h=1: +64*8
    }
}

// ---------------- MFMA GEMM ----------------
// Y16 layout is CHUNK-MAJOR: Y[(nt*N + row)*16 + m], chunk = nt (16 features).
// Two input pointers: columns [0,K1) from X1 (stride K1), [K1,K) from X2 (stride K-K1).

__device__ __forceinline__ void split8(const float* v, shortx8& hi, shortx8& lo) {
#pragma unroll
    for (int i = 0; i < 8; i++) {
        unsigned u = __float_as_uint(v[i]);
        float r = v[i] - __uint_as_float(u & 0xFFFF0000u);
        hi[i] = (short)(u >> 16);
        lo[i] = (short)(__float_as_uint(r) >> 16);
    }
}

template <int OUT, int K, int K1>
__global__ __launch_bounds__(512)
void gemm_mfma(const float* __restrict__ X1, const float* __restrict__ X2,
               const unsigned short* __restrict__ Wsw,
               const float* __restrict__ dinv,
               __half* __restrict__ Y, int ntiles) {
    constexpr int NT = OUT / 16;
    constexpr int NKTC = K / 32;
    constexpr int K2 = K - K1;
    constexpr int PERC = OUT * 128;  // bytes per ktc chunk
    constexpr int CSZ = (65536 / PERC < NKTC) ? (65536 / PERC) : NKTC;
    __shared__ __align__(16) unsigned short lds[CSZ * PERC / 2];

    const int t = threadIdx.x;
    const int wave = t >> 6, lane = t & 63;
    const int m = lane & 15, q = lane >> 4;
    const int tile = blockIdx.x * 8 + wave;
    const bool act = tile < ntiles;
    const int row = act ? tile * 16 + m : 0;
    const int nfull = ntiles * 16;
    const float* ap1 = X1 + (size_t)row * K1 + q * 8;
    const float* ap2 = (K2 > 0) ? (X2 + (size_t)row * K2 + q * 8) : X1;

    floatx4 acc[NT];
#pragma unroll
    for (int nt = 0; nt < NT; nt++) acc[nt] = (floatx4){0.f, 0.f, 0.f, 0.f};

#pragma unroll
    for (int c0 = 0; c0 < NKTC; c0 += CSZ) {
        const int cl = (NKTC - c0 < CSZ) ? (NKTC - c0) : CSZ;
        if (c0 != 0) __syncthreads();
        {
            const float4* gs = (const float4*)Wsw + (size_t)c0 * (PERC / 16);
            float4* ld = (float4*)lds;
            int tot = cl * (PERC / 16);
            for (int i = t; i < tot; i += 512) ld[i] = gs[i];
        }
        __syncthreads();
        if (act) {
#pragma unroll
            for (int ktc = 0; ktc < cl; ktc++) {
                const int kg = (c0 + ktc) * 32;
                const float* p = (kg < K1) ? (ap1 + kg) : (ap2 + (kg - K1));
                float av[8];
                *(float4*)&av[0] = *(const float4*)(p);
                *(float4*)&av[4] = *(const float4*)(p + 4);
                shortx8 ahi, alo;
                split8(av, ahi, alo);
#pragma unroll
                for (int nt = 0; nt < NT; nt++) {
                    const unsigned short* fb =
                        lds + ((((ktc * NT + nt) * 2) * 64 + lane) << 3);
                    shortx8 bhi = *(const shortx8*)fb;
                    shortx8 blo = *(const shortx8*)(fb + 512);
                    acc[nt] = __builtin_amdgcn_mfma_f32_16x16x32_bf16(ahi, bhi, acc[nt], 0, 0, 0);
                    acc[nt] = __builtin_amdgcn_mfma_f32_16x16x32_bf16(ahi, blo, acc[nt], 0, 0, 0);
                    acc[nt] = __builtin_amdgcn_mfma_f32_16x16x32_bf16(alo, bhi, acc[nt], 0, 0, 0);
                }
            }
        }
    }

    if (act) {
        float di[4];
#pragma unroll
        for (int r = 0; r < 4; r++) di[r] = dinv[tile * 16 + q * 4 + r];
#pragma unroll
        for (int nt = 0; nt < NT; nt++) {
#pragma unroll
            for (int r = 0; r < 4; r++) {
                int orow = tile * 16 + q * 4 + r;
                Y[((size_t)nt * nfull + orow) * 16 + m] =
                    __float2half_rn(acc[nt][r] * di[r]);
            }
        }
    }
}

// ---------------- chunked propagation, slot-per-node ----------------
// H16 chunk-major: base = hs + c*n*8 (half2 units); 32 B per (node, chunk).
// chunk = blockIdx % NCH -> XCD round-robin pins each 3.2 MB chunk slice to
// one XCD's L2 (round-1 verified: FETCH 192 MB -> 43 MB).
// Wave = 8 slots x 8 feature lanes. Slot owns ONE node's whole edge list and
// accumulates privately -> no cross-lane reduce; block covers 64 nodes, so the
// wave count stays at 100K/prop (round-1's 800K waves was the regression).
// Unroll-4 gather loop: up to 32 independent gathers in flight per wave.

template <int NCH, bool TANH>
__global__ __launch_bounds__(512)
void prop_slot(const __half2* __restrict__ hs, const float* __restrict__ dinv,
               const int* __restrict__ rowptr, const int* __restrict__ colid,
               const float* __restrict__ bias, float* __restrict__ out,
               int ldo, int n) {
    int bid = blockIdx.x;
    int c = bid & (NCH - 1);
    int nb = bid / NCH;
    int wave = threadIdx.x >> 6, lane = threadIdx.x & 63;
    int slot = lane >> 3, f = lane & 7;
    int node = nb * 64 + wave * 8 + slot;
    if (node >= n) return;
    int beg = rowptr[node], end = rowptr[node + 1];
    const __half2* __restrict__ base = hs + (size_t)c * (size_t)n * 8;

    float ax = 0.f, ay = 0.f, bx = 0.f, by = 0.f;
    int e = beg;
    for (; e + 4 <= end; e += 4) {
        int s0 = __builtin_nontemporal_load(colid + e);
        int s1 = __builtin_nontemporal_load(colid + e + 1);
        int s2 = __builtin_nontemporal_load(colid + e + 2);
        int s3 = __builtin_nontemporal_load(colid + e + 3);
        float2 v0 = __half22float2(base[(unsigned)(s0 * 8 + f)]);
        float2 v1 = __half22float2(base[(unsigned)(s1 * 8 + f)]);
        float2 v2 = __half22float2(base[(unsigned)(s2 * 8 + f)]);
        float2 v3 = __half22float2(base[(unsigned)(s3 * 8 + f)]);
        ax += v0.x + v2.x; ay += v0.y + v2.y;
        bx += v1.x + v3.x; by += v1.y + v3.y;
    }
    for (; e < end; e++) {
        int s = __builtin_nontemporal_load(colid + e);
        float2 v = __half22float2(base[(unsigned)(s * 8 + f)]);
        ax += v.x; ay += v.y;
    }
    float2 sf = __half22float2(base[(unsigned)(node * 8 + f)]);
    float di = dinv[node];
    float2 bb = *(const float2*)(bias + c * 16 + 2 * f);
    float ox = di * (ax + bx + sf.x) + bb.x;
    float oy = di * (ay + by + sf.y) + bb.y;
    if (TANH) { ox = tanhf(ox); oy = tanhf(oy); }
    *(float2*)(out + (size_t)node * ldo + c * 16 + 2 * f) = make_float2(ox, oy);
}

// ---------------- launch ----------------

extern "C" void kernel_launch(void* const* d_in, const int* in_sizes, int n_in,
                              void* d_out, int out_size, void* d_ws, size_t ws_size,
                              hipStream_t stream) {
    const int n = NN, E = NE;
    const float* feature   = (const float*)d_in[0];
    const float* condition = (const float*)d_in[1];
    const int*   ei        = (const int*)d_in[2];
    const float* W_e1 = (const float*)d_in[3];  const float* b_e1 = (const float*)d_in[4];
    const float* W_e2 = (const float*)d_in[5];  const float* b_e2 = (const float*)d_in[6];
    const float* W_e3 = (const float*)d_in[7];  const float* b_e3 = (const float*)d_in[8];
    const float* W_d1 = (const float*)d_in[9];  const float* b_d1 = (const float*)d_in[10];
    const float* W_d2 = (const float*)d_in[11]; const float* b_d2 = (const float*)d_in[12];
    const float* W_d3 = (const float*)d_in[13]; const float* b_d3 = (const float*)d_in[14];
    float* out = (float*)d_out;

    float*  A    = (float*)d_ws;                    // n*160 floats
    __half* H16  = (__half*)(A + (size_t)n * 160);  // n*128 halves
    float*  dinv = (float*)(H16 + (size_t)n * 128); // n
    int* rowptr  = (int*)(dinv + n);                // n+1
    int* colid   = rowptr + n + 1;                  // E
    uintptr_t pp = (uintptr_t)(colid + E);
    pp = (pp + 15) & ~(uintptr_t)15;
    unsigned long long* pairs = (unsigned long long*)pp;  // E
    int* bucket_cnt  = (int*)(pairs + E);           // 512
    int* bucket_base = bucket_cnt + 512;            // 512
    int* bucket_fill = bucket_base + 512;           // 512
    uintptr_t wp = (uintptr_t)(bucket_fill + 512);
    wp = (wp + 15) & ~(uintptr_t)15;
    unsigned short* wt = (unsigned short*)wp;
    unsigned short* e1w = wt;              unsigned short* e2w = e1w + 160 * 128 * 2;
    unsigned short* e3w = e2w + 128*128*2; unsigned short* d1w = e3w + 128 * 64 * 2;
    unsigned short* d2w = d1w + 96*128*2;  unsigned short* d3w = d2w + 128 * 128 * 2;

    hipMemsetAsync(bucket_cnt, 0, 512 * sizeof(int), stream);

    int nbc = (E + CHUNK - 1) / CHUNK;
    coarse_hist<<<nbc, 256, 0, stream>>>(ei, bucket_cnt, E);
    scan_buckets<<<1, 512, 0, stream>>>(bucket_cnt, bucket_base, bucket_fill);
    coarse_scatter<<<nbc, 256, 0, stream>>>(ei, bucket_fill, pairs, E);
    fine_csr<<<NB, 256, 0, stream>>>(pairs, bucket_base, rowptr, colid, dinv, n);

    wsplit_kernel<<<(160*128 + 255)/256, 256, 0, stream>>>(W_e1, e1w, 160, 128);
    wsplit_kernel<<<(128*128 + 255)/256, 256, 0, stream>>>(W_e2, e2w, 128, 128);
    wsplit_kernel<<<(128*64  + 255)/256, 256, 0, stream>>>(W_e3, e3w, 128, 64);
    wsplit_kernel<<<(96*128  + 255)/256, 256, 0, stream>>>(W_d1, d1w, 96, 128);
    wsplit_kernel<<<(128*128 + 255)/256, 256, 0, stream>>>(W_d2, d2w, 128, 128);
    wsplit_kernel<<<(128*128 + 255)/256, 256, 0, stream>>>(W_d3, d3w, 128, 128);

    const int ntiles = n / 16;          // 6250 exactly
    const int gb = (ntiles + 7) / 8;    // 8 waves per block
    const int nblk = (n + 63) / 64;     // 1563 node-blocks (64 nodes/block)

    // encoder (e1 reads feature+condition directly)
    gemm_mfma<128, 160, 128><<<gb, 512, 0, stream>>>(feature, condition, e1w, dinv, H16, ntiles);
    prop_slot<8, true><<<8 * nblk, 512, 0, stream>>>((const __half2*)H16, dinv, rowptr, colid, b_e1, A, 128, n);
    gemm_mfma<128, 128, 128><<<gb, 512, 0, stream>>>(A, nullptr, e2w, dinv, H16, ntiles);
    prop_slot<8, true><<<8 * nblk, 512, 0, stream>>>((const __half2*)H16, dinv, rowptr, colid, b_e2, A, 128, n);
    gemm_mfma<64, 128, 128><<<gb, 512, 0, stream>>>(A, nullptr, e3w, dinv, H16, ntiles);
    prop_slot<4, false><<<4 * nblk, 512, 0, stream>>>((const __half2*)H16, dinv, rowptr, colid, b_e3, A, 64, n);

    // decoder (d1 reads z (ld=64) + condition directly)
    gemm_mfma<128, 96, 64><<<gb, 512, 0, stream>>>(A, condition, d1w, dinv, H16, ntiles);
    prop_slot<8, true><<<8 * nblk, 512, 0, stream>>>((const __half2*)H16, dinv, rowptr, colid, b_d1, A, 128, n);
    gemm_mfma<128, 128, 128><<<gb, 512, 0, stream>>>(A, nullptr, d2w, dinv, H16, ntiles);
    prop_slot<8, true><<<8 * nblk, 512, 0, stream>>>((const __half2*)H16, dinv, rowptr, colid, b_d2, A, 128, n);
    gemm_mfma<128, 128, 128><<<gb, 512, 0, stream>>>(A, nullptr, d3w, dinv, H16, ntiles);
    prop_slot<8, false><<<8 * nblk, 512, 0, stream>>>((const __half2*)H16, dinv, rowptr, colid, b_d3, out, 128, n);
}

// Round 3
// 702.902 us; speedup vs baseline: 2.5363x; 1.8541x over previous
//
#include <hip/hip_runtime.h>
#include <hip/hip_fp16.h>
#include <math.h>

#define NN 100000
#define NE 1600000
#define NB ((NN + 255) >> 8)   // 391 buckets of 256 nodes
#define CHUNK 8192
#define CAP 8192

typedef __attribute__((ext_vector_type(4))) float floatx4;
typedef __attribute__((ext_vector_type(8))) short shortx8;

// ---------------- bucketed CSR build ----------------

__global__ __launch_bounds__(256)
void coarse_hist(const int* __restrict__ ei, int* __restrict__ bucket_cnt, int E) {
    __shared__ int h[512];
    int t = threadIdx.x;
    for (int i = t; i < 512; i += 256) h[i] = 0;
    __syncthreads();
    int base = blockIdx.x * CHUNK;
    int lim = min(base + CHUNK, E);
    for (int e = base + t; e < lim; e += 256) {
        int d = ei[E + e];
        atomicAdd(&h[d >> 8], 1);
    }
    __syncthreads();
    for (int i = t; i < 512; i += 256)
        if (h[i]) atomicAdd(&bucket_cnt[i], h[i]);
}

__global__ void scan_buckets(const int* __restrict__ bucket_cnt,
                             int* __restrict__ bucket_base,
                             int* __restrict__ bucket_fill) {
    __shared__ int sh[512];
    int t = threadIdx.x;  // 512 threads
    int v = (t < NB) ? bucket_cnt[t] : 0;
    sh[t] = v;
    __syncthreads();
    for (int off = 1; off < 512; off <<= 1) {
        int u = (t >= off) ? sh[t - off] : 0;
        __syncthreads();
        sh[t] += u;
        __syncthreads();
    }
    int ex = (t == 0) ? 0 : sh[t - 1];
    if (t <= NB) bucket_base[t] = ex;
    if (t < NB) bucket_fill[t] = ex;
}

__global__ __launch_bounds__(256)
void coarse_scatter(const int* __restrict__ ei, int* __restrict__ bucket_fill,
                    unsigned long long* __restrict__ pairs, int E) {
    __shared__ int h[512];
    __shared__ int base[512];
    int t = threadIdx.x;
    for (int i = t; i < 512; i += 256) h[i] = 0;
    __syncthreads();
    int cbase = blockIdx.x * CHUNK;
    int lim = min(cbase + CHUNK, E);
    for (int e = cbase + t; e < lim; e += 256) {
        int d = ei[E + e];
        atomicAdd(&h[d >> 8], 1);
    }
    __syncthreads();
    for (int i = t; i < 512; i += 256)
        base[i] = h[i] ? atomicAdd(&bucket_fill[i], h[i]) : 0;
    __syncthreads();
    for (int i = t; i < 512; i += 256) h[i] = 0;
    __syncthreads();
    for (int e = cbase + t; e < lim; e += 256) {
        int s = ei[e];
        int d = ei[E + e];
        int b = d >> 8;
        int r = atomicAdd(&h[b], 1);
        pairs[base[b] + r] =
            ((unsigned long long)(unsigned)d << 32) | (unsigned)s;
    }
}

__global__ __launch_bounds__(256)
void fine_csr(const unsigned long long* __restrict__ pairs,
              const int* __restrict__ bucket_base,
              int* __restrict__ rowptr, int* __restrict__ colid,
              float* __restrict__ dinv, int n) {
    __shared__ int hist[256];
    __shared__ int offs[256];
    __shared__ int rank[256];
    __shared__ int lbuf[CAP];
    int b = blockIdx.x, t = threadIdx.x;
    int beg = bucket_base[b], end = bucket_base[b + 1];
    int cnt = end - beg;
    hist[t] = 0; rank[t] = 0;
    __syncthreads();
    for (int i = t; i < cnt; i += 256) {
        int d = (int)(pairs[beg + i] >> 32);
        atomicAdd(&hist[d & 255], 1);
    }
    __syncthreads();
    int v = hist[t];
    offs[t] = v;
    __syncthreads();
    for (int off = 1; off < 256; off <<= 1) {
        int u = (t >= off) ? offs[t - off] : 0;
        __syncthreads();
        offs[t] += u;
        __syncthreads();
    }
    int ex = (t == 0) ? 0 : offs[t - 1];
    int node = (b << 8) + t;
    if (node < n) {
        rowptr[node] = beg + ex;
        dinv[node] = rsqrtf((float)v + 1.0f);
    } else if (node == n) {
        rowptr[n] = beg + ex;
    }
    __syncthreads();
    offs[t] = ex;
    __syncthreads();
    for (int i = t; i < cnt; i += 256) {
        unsigned long long p = pairs[beg + i];
        int d = (int)(p >> 32) & 255;
        int s = (int)(p & 0xffffffffu);
        int r = atomicAdd(&rank[d], 1);
        lbuf[offs[d] + r] = s;
    }
    __syncthreads();
    for (int i = t; i < cnt; i += 256) colid[beg + i] = lbuf[i];
}

// ---------------- weight prep: W[K][OUT] fp32 -> swizzled bf16 hi/lo fragments ----
// all 6 layers in ONE launch (segment dispatch on flat index).

__device__ __forceinline__ void wsplit_one(const float* __restrict__ W,
                                           unsigned short* __restrict__ Wsw,
                                           int i, int K, int OUT) {
    int k = i / OUT, o = i % OUT;
    float w = W[i];
    unsigned u = __float_as_uint(w);
    float r = w - __uint_as_float(u & 0xFFFF0000u);
    int NT = OUT >> 4;
    int ktc = k >> 5, q = (k >> 3) & 3, j = k & 7;
    int nt = o >> 4, mm = o & 15;
    int lane = (q << 4) | mm;
    size_t base = ((((size_t)(ktc * NT + nt) * 2) * 64 + lane) << 3) + j;
    Wsw[base] = (unsigned short)(u >> 16);
    Wsw[base + 512] = (unsigned short)(__float_as_uint(r) >> 16);  // h=1: +64*8
}

__global__ __launch_bounds__(256)
void wsplit_all(const float* __restrict__ W0, unsigned short* __restrict__ O0,
                const float* __restrict__ W1, unsigned short* __restrict__ O1,
                const float* __restrict__ W2, unsigned short* __restrict__ O2,
                const float* __restrict__ W3, unsigned short* __restrict__ O3,
                const float* __restrict__ W4, unsigned short* __restrict__ O4,
                const float* __restrict__ W5, unsigned short* __restrict__ O5) {
    int i = blockIdx.x * 256 + threadIdx.x;
    // sizes: e1 20480, e2 16384, e3 8192, d1 12288, d2 16384, d3 16384
    if (i < 20480) { wsplit_one(W0, O0, i, 160, 128); return; }
    i -= 20480;
    if (i < 16384) { wsplit_one(W1, O1, i, 128, 128); return; }
    i -= 16384;
    if (i < 8192)  { wsplit_one(W2, O2, i, 128, 64);  return; }
    i -= 8192;
    if (i < 12288) { wsplit_one(W3, O3, i, 96, 128);  return; }
    i -= 12288;
    if (i < 16384) { wsplit_one(W4, O4, i, 128, 128); return; }
    i -= 16384;
    if (i < 16384) { wsplit_one(W5, O5, i, 128, 128); }
}

// ---------------- MFMA GEMM ----------------
// Y16 row-major: Y[row*OUT + o], fp16.
// Two input pointers: columns [0,K1) from X1 (stride K1), [K1,K) from X2 (stride K-K1).

__device__ __forceinline__ void split8(const float* v, shortx8& hi, shortx8& lo) {
#pragma unroll
    for (int i = 0; i < 8; i++) {
        unsigned u = __float_as_uint(v[i]);
        float r = v[i] - __uint_as_float(u & 0xFFFF0000u);
        hi[i] = (short)(u >> 16);
        lo[i] = (short)(__float_as_uint(r) >> 16);
    }
}

template <int OUT, int K, int K1>
__global__ __launch_bounds__(512)
void gemm_mfma(const float* __restrict__ X1, const float* __restrict__ X2,
               const unsigned short* __restrict__ Wsw,
               const float* __restrict__ dinv,
               __half* __restrict__ Y, int ntiles) {
    constexpr int NT = OUT / 16;
    constexpr int NKTC = K / 32;
    constexpr int K2 = K - K1;
    constexpr int PERC = OUT * 128;  // bytes per ktc chunk
    constexpr int CSZ = (65536 / PERC < NKTC) ? (65536 / PERC) : NKTC;
    __shared__ __align__(16) unsigned short lds[CSZ * PERC / 2];

    const int t = threadIdx.x;
    const int wave = t >> 6, lane = t & 63;
    const int m = lane & 15, q = lane >> 4;
    const int tile = blockIdx.x * 8 + wave;
    const bool act = tile < ntiles;
    const int row = act ? tile * 16 + m : 0;
    const float* ap1 = X1 + (size_t)row * K1 + q * 8;
    const float* ap2 = (K2 > 0) ? (X2 + (size_t)row * K2 + q * 8) : X1;

    floatx4 acc[NT];
#pragma unroll
    for (int nt = 0; nt < NT; nt++) acc[nt] = (floatx4){0.f, 0.f, 0.f, 0.f};

#pragma unroll
    for (int c0 = 0; c0 < NKTC; c0 += CSZ) {
        const int cl = (NKTC - c0 < CSZ) ? (NKTC - c0) : CSZ;
        if (c0 != 0) __syncthreads();
        {
            const float4* gs = (const float4*)Wsw + (size_t)c0 * (PERC / 16);
            float4* ld = (float4*)lds;
            int tot = cl * (PERC / 16);
            for (int i = t; i < tot; i += 512) ld[i] = gs[i];
        }
        __syncthreads();
        if (act) {
#pragma unroll
            for (int ktc = 0; ktc < cl; ktc++) {
                const int kg = (c0 + ktc) * 32;
                const float* p = (kg < K1) ? (ap1 + kg) : (ap2 + (kg - K1));
                float av[8];
                *(float4*)&av[0] = *(const float4*)(p);
                *(float4*)&av[4] = *(const float4*)(p + 4);
                shortx8 ahi, alo;
                split8(av, ahi, alo);
#pragma unroll
                for (int nt = 0; nt < NT; nt++) {
                    const unsigned short* fb =
                        lds + ((((ktc * NT + nt) * 2) * 64 + lane) << 3);
                    shortx8 bhi = *(const shortx8*)fb;
                    shortx8 blo = *(const shortx8*)(fb + 512);
                    acc[nt] = __builtin_amdgcn_mfma_f32_16x16x32_bf16(ahi, bhi, acc[nt], 0, 0, 0);
                    acc[nt] = __builtin_amdgcn_mfma_f32_16x16x32_bf16(ahi, blo, acc[nt], 0, 0, 0);
                    acc[nt] = __builtin_amdgcn_mfma_f32_16x16x32_bf16(alo, bhi, acc[nt], 0, 0, 0);
                }
            }
        }
    }

    if (act) {
        float di[4];
#pragma unroll
        for (int r = 0; r < 4; r++) di[r] = dinv[tile * 16 + q * 4 + r];
#pragma unroll
        for (int nt = 0; nt < NT; nt++) {
#pragma unroll
            for (int r = 0; r < 4; r++) {
                int orow = tile * 16 + q * 4 + r;
                Y[(size_t)orow * OUT + nt * 16 + m] =
                    __float2half_rn(acc[nt][r] * di[r]);
            }
        }
    }
}

// ---------------- propagation: row-major gather, G edges per instruction ----------------
// Wave = 1 node. Lane loads 8 B (4 halfs) of a source row; LPR = OUT/4 lanes
// cover one row, so G = 64/LPR edges are gathered PER INSTRUCTION (G=2 for
// OUT=128, G=4 for OUT=64). Halves gather+colid+VALU instruction count vs the
// round-0 one-edge-per-instruction kernel at identical traffic and locality.
// Cross-group shfl_xor reduce; self-loop/bias/tanh/store in group 0 only.

template <int OUT, bool TANH>
__global__ __launch_bounds__(256)
void prop_row(const __half2* __restrict__ hs, const float* __restrict__ dinv,
              const int* __restrict__ rowptr, const int* __restrict__ colid,
              const float* __restrict__ bias, float* __restrict__ out,
              int ldo, int n) {
    constexpr int LPR = OUT / 4;   // lanes per row (8 B per lane)
    constexpr int G = 64 / LPR;    // edges per gather instruction
    constexpr int RS2 = OUT / 4;   // float2 (2x half2) per row

    int wave = threadIdx.x >> 6, lane = threadIdx.x & 63;
    int node = blockIdx.x * 4 + wave;
    if (node >= n) return;
    int g = lane / LPR, fq = lane % LPR;
    int beg = rowptr[node], end = rowptr[node + 1];
    const float2* __restrict__ b2 = (const float2*)hs;

    float ax = 0.f, ay = 0.f, az = 0.f, aw = 0.f;
    int e = beg;
    for (; e + 8 * G <= end; e += 8 * G) {
        int s[8];
#pragma unroll
        for (int j = 0; j < 8; j++) s[j] = colid[e + j * G + g];
        float2 v[8];
#pragma unroll
        for (int j = 0; j < 8; j++) v[j] = b2[(size_t)s[j] * RS2 + fq];
#pragma unroll
        for (int j = 0; j < 8; j++) {
            float2 f0 = __half22float2(*(const __half2*)&v[j].x);
            float2 f1 = __half22float2(*(const __half2*)&v[j].y);
            ax += f0.x; ay += f0.y; az += f1.x; aw += f1.y;
        }
    }
    if (e + 4 * G <= end) {
        int s[4];
#pragma unroll
        for (int j = 0; j < 4; j++) s[j] = colid[e + j * G + g];
        float2 v[4];
#pragma unroll
        for (int j = 0; j < 4; j++) v[j] = b2[(size_t)s[j] * RS2 + fq];
#pragma unroll
        for (int j = 0; j < 4; j++) {
            float2 f0 = __half22float2(*(const __half2*)&v[j].x);
            float2 f1 = __half22float2(*(const __half2*)&v[j].y);
            ax += f0.x; ay += f0.y; az += f1.x; aw += f1.y;
        }
        e += 4 * G;
    }
    for (; e + G <= end; e += G) {
        int s = colid[e + g];
        float2 v = b2[(size_t)s * RS2 + fq];
        float2 f0 = __half22float2(*(const __half2*)&v.x);
        float2 f1 = __half22float2(*(const __half2*)&v.y);
        ax += f0.x; ay += f0.y; az += f1.x; aw += f1.y;
    }
    if (e + g < end) {
        int s = colid[e + g];
        float2 v = b2[(size_t)s * RS2 + fq];
        float2 f0 = __half22float2(*(const __half2*)&v.x);
        float2 f1 = __half22float2(*(const __half2*)&v.y);
        ax += f0.x; ay += f0.y; az += f1.x; aw += f1.y;
    }

    // reduce across the G edge-groups (lanes differing in group bits)
    if constexpr (G >= 2) {
        ax += __shfl_xor(ax, LPR); ay += __shfl_xor(ay, LPR);
        az += __shfl_xor(az, LPR); aw += __shfl_xor(aw, LPR);
    }
    if constexpr (G == 4) {
        ax += __shfl_xor(ax, 2 * LPR); ay += __shfl_xor(ay, 2 * LPR);
        az += __shfl_xor(az, 2 * LPR); aw += __shfl_xor(aw, 2 * LPR);
    }

    if (g == 0) {
        float2 sv = b2[(size_t)node * RS2 + fq];
        float2 f0 = __half22float2(*(const __half2*)&sv.x);
        float2 f1 = __half22float2(*(const __half2*)&sv.y);
        ax += f0.x; ay += f0.y; az += f1.x; aw += f1.y;
        float di = dinv[node];
        float4 bb = *(const float4*)(bias + fq * 4);
        float ox = di * ax + bb.x;
        float oy = di * ay + bb.y;
        float oz = di * az + bb.z;
        float ow = di * aw + bb.w;
        if (TANH) { ox = tanhf(ox); oy = tanhf(oy); oz = tanhf(oz); ow = tanhf(ow); }
        *(float4*)(out + (size_t)node * ldo + fq * 4) = make_float4(ox, oy, oz, ow);
    }
}

// ---------------- launch ----------------

extern "C" void kernel_launch(void* const* d_in, const int* in_sizes, int n_in,
                              void* d_out, int out_size, void* d_ws, size_t ws_size,
                              hipStream_t stream) {
    const int n = NN, E = NE;
    const float* feature   = (const float*)d_in[0];
    const float* condition = (const float*)d_in[1];
    const int*   ei        = (const int*)d_in[2];
    const float* W_e1 = (const float*)d_in[3];  const float* b_e1 = (const float*)d_in[4];
    const float* W_e2 = (const float*)d_in[5];  const float* b_e2 = (const float*)d_in[6];
    const float* W_e3 = (const float*)d_in[7];  const float* b_e3 = (const float*)d_in[8];
    const float* W_d1 = (const float*)d_in[9];  const float* b_d1 = (const float*)d_in[10];
    const float* W_d2 = (const float*)d_in[11]; const float* b_d2 = (const float*)d_in[12];
    const float* W_d3 = (const float*)d_in[13]; const float* b_d3 = (const float*)d_in[14];
    float* out = (float*)d_out;

    float*  A    = (float*)d_ws;                    // n*160 floats
    __half* H16  = (__half*)(A + (size_t)n * 160);  // n*128 halves
    float*  dinv = (float*)(H16 + (size_t)n * 128); // n
    int* rowptr  = (int*)(dinv + n);                // n+1
    int* colid   = rowptr + n + 1;                  // E
    uintptr_t pp = (uintptr_t)(colid + E);
    pp = (pp + 15) & ~(uintptr_t)15;
    unsigned long long* pairs = (unsigned long long*)pp;  // E
    int* bucket_cnt  = (int*)(pairs + E);           // 512
    int* bucket_base = bucket_cnt + 512;            // 512
    int* bucket_fill = bucket_base + 512;           // 512
    uintptr_t wp = (uintptr_t)(bucket_fill + 512);
    wp = (wp + 15) & ~(uintptr_t)15;
    unsigned short* wt = (unsigned short*)wp;
    unsigned short* e1w = wt;              unsigned short* e2w = e1w + 160 * 128 * 2;
    unsigned short* e3w = e2w + 128*128*2; unsigned short* d1w = e3w + 128 * 64 * 2;
    unsigned short* d2w = d1w + 96*128*2;  unsigned short* d3w = d2w + 128 * 128 * 2;

    hipMemsetAsync(bucket_cnt, 0, 512 * sizeof(int), stream);

    int nbc = (E + CHUNK - 1) / CHUNK;
    coarse_hist<<<nbc, 256, 0, stream>>>(ei, bucket_cnt, E);
    scan_buckets<<<1, 512, 0, stream>>>(bucket_cnt, bucket_base, bucket_fill);
    coarse_scatter<<<nbc, 256, 0, stream>>>(ei, bucket_fill, pairs, E);
    fine_csr<<<NB, 256, 0, stream>>>(pairs, bucket_base, rowptr, colid, dinv, n);

    wsplit_all<<<(90112 + 255) / 256, 256, 0, stream>>>(
        W_e1, e1w, W_e2, e2w, W_e3, e3w, W_d1, d1w, W_d2, d2w, W_d3, d3w);

    const int ntiles = n / 16;          // 6250 exactly
    const int gb = (ntiles + 7) / 8;    // 8 waves per block
    const int pb = (n + 3) / 4;         // 25000 blocks, 1 wave per node

    // encoder (e1 reads feature+condition directly; no concat)
    gemm_mfma<128, 160, 128><<<gb, 512, 0, stream>>>(feature, condition, e1w, dinv, H16, ntiles);
    prop_row<128, true><<<pb, 256, 0, stream>>>((const __half2*)H16, dinv, rowptr, colid, b_e1, A, 128, n);
    gemm_mfma<128, 128, 128><<<gb, 512, 0, stream>>>(A, nullptr, e2w, dinv, H16, ntiles);
    prop_row<128, true><<<pb, 256, 0, stream>>>((const __half2*)H16, dinv, rowptr, colid, b_e2, A, 128, n);
    gemm_mfma<64, 128, 128><<<gb, 512, 0, stream>>>(A, nullptr, e3w, dinv, H16, ntiles);
    prop_row<64, false><<<pb, 256, 0, stream>>>((const __half2*)H16, dinv, rowptr, colid, b_e3, A, 64, n);

    // decoder (d1 reads z (ld=64) + condition directly; no condcopy)
    gemm_mfma<128, 96, 64><<<gb, 512, 0, stream>>>(A, condition, d1w, dinv, H16, ntiles);
    prop_row<128, true><<<pb, 256, 0, stream>>>((const __half2*)H16, dinv, rowptr, colid, b_d1, A, 128, n);
    gemm_mfma<128, 128, 128><<<gb, 512, 0, stream>>>(A, nullptr, d2w, dinv, H16, ntiles);
    prop_row<128, true><<<pb, 256, 0, stream>>>((const __half2*)H16, dinv, rowptr, colid, b_d2, A, 128, n);
    gemm_mfma<128, 128, 128><<<gb, 512, 0, stream>>>(A, nullptr, d3w, dinv, H16, ntiles);
    prop_row<128, false><<<pb, 256, 0, stream>>>((const __half2*)H16, dinv, rowptr, colid, b_d3, out, 128, n);
}